// Round 3
// baseline (304.556 us; speedup 1.0000x reference)
//
#include <hip/hip_runtime.h>

#define PXW 1920.0f
#define PXH 1080.0f
#define RELAXF 1.3f

// One thread processes 4 points so every global access is an aligned float4:
// pos3d: 3 x float4 per thread, cov3d: 9 x float4, pos2d: 3 x float4,
// cov2d: 4 x float4, mask: 1 x float4. Fully coalesced (G13).
__global__ __launch_bounds__(256) void cam_kernel(
    const float* __restrict__ pos3d,
    const float* __restrict__ cov3d,
    const float* __restrict__ view,
    const float* __restrict__ proj,
    float* __restrict__ out,   // [pos2d 3n | cov2d 4n | mask n]
    int n)
{
  const int g = blockIdx.x * blockDim.x + threadIdx.x;
  if (g * 4 >= n) return;   // n % 4 == 0 in this problem (N = 4,000,000)

  // Uniform (wave-invariant) matrix loads -> scalar loads + broadcast.
  float V[12];
  float P[16];
#pragma unroll
  for (int i = 0; i < 12; ++i) V[i] = view[i];
#pragma unroll
  for (int i = 0; i < 16; ++i) P[i] = proj[i];

  // ---- load 4 points ----
  const float4* p4 = reinterpret_cast<const float4*>(pos3d) + (size_t)3 * g;
  const float4 pa = p4[0], pb = p4[1], pc = p4[2];
  float px[4], py[4], pz[4];
  px[0] = pa.x; py[0] = pa.y; pz[0] = pa.z;
  px[1] = pa.w; py[1] = pb.x; pz[1] = pb.y;
  px[2] = pb.z; py[2] = pb.w; pz[2] = pc.x;
  px[3] = pc.y; py[3] = pc.z; pz[3] = pc.w;

  const float4* c4 = reinterpret_cast<const float4*>(cov3d) + (size_t)9 * g;
  float cf[36];
#pragma unroll
  for (int i = 0; i < 9; ++i) {
    const float4 t = c4[i];
    cf[4 * i + 0] = t.x; cf[4 * i + 1] = t.y;
    cf[4 * i + 2] = t.z; cf[4 * i + 3] = t.w;
  }

  float o_pos[12];
  float o_cov[16];
  float o_msk[4];

#pragma unroll
  for (int k = 0; k < 4; ++k) {
    const float x = px[k], y = py[k], z = pz[k];

    // p_model = view[:3,:3] @ p + view[:3,3]   (row-major V)
    const float pm0 = V[0] * x + V[1] * y + V[2]  * z + V[3];
    const float pm1 = V[4] * x + V[5] * y + V[6]  * z + V[7];
    const float pm2 = V[8] * x + V[9] * y + V[10] * z + V[11];

    // clip = P @ [pm, 1]
    const float c0 = P[0]  * pm0 + P[1]  * pm1 + P[2]  * pm2 + P[3];
    const float c1 = P[4]  * pm0 + P[5]  * pm1 + P[6]  * pm2 + P[7];
    const float c2 = P[8]  * pm0 + P[9]  * pm1 + P[10] * pm2 + P[11];
    const float c3 = P[12] * pm0 + P[13] * pm1 + P[14] * pm2 + P[15];

    const float iw = 1.0f / (c3 + 1e-6f);
    const float nx = c0 * iw, ny = c1 * iw, nz = c2 * iw;

    const bool m = (nz >= 0.2f) && (nx >= -RELAXF) && (nx <= RELAXF)
                                && (ny >= -RELAXF) && (ny <= RELAXF);

    const float sx = 0.5f * (nx + 1.0f) * PXW;
    const float sy = (1.0f - 0.5f * (ny + 1.0f)) * PXH;

    o_pos[3 * k + 0] = m ? sx : 0.0f;
    o_pos[3 * k + 1] = m ? sy : 0.0f;
    o_pos[3 * k + 2] = m ? nz : 0.0f;
    o_msk[k]         = m ? 1.0f : 0.0f;

    // JW = J @ Wm, Wm = view[:3,:3]^T  =>  Wm[r][c] = V[4c + r]
    const float iz = 1.0f / z;
    const float a0 = iz * (V[0] - x * V[2]);
    const float a1 = iz * (V[4] - x * V[6]);
    const float a2 = iz * (V[8] - x * V[10]);
    const float b0 = iz * (V[1] - y * V[2]);
    const float b1 = iz * (V[5] - y * V[6]);
    const float b2 = iz * (V[9] - y * V[10]);

    const float* C = &cf[9 * k];
    const float u0 = C[0] * a0 + C[1] * a1 + C[2] * a2;
    const float u1 = C[3] * a0 + C[4] * a1 + C[5] * a2;
    const float u2 = C[6] * a0 + C[7] * a1 + C[8] * a2;
    const float v0 = C[0] * b0 + C[1] * b1 + C[2] * b2;
    const float v1 = C[3] * b0 + C[4] * b1 + C[5] * b2;
    const float v2 = C[6] * b0 + C[7] * b1 + C[8] * b2;

    const float c00 = a0 * u0 + a1 * u1 + a2 * u2;
    const float c01 = a0 * v0 + a1 * v1 + a2 * v2;
    const float c10 = b0 * u0 + b1 * u1 + b2 * u2;
    const float c11 = b0 * v0 + b1 * v1 + b2 * v2;

    o_cov[4 * k + 0] = m ? c00 : 0.0f;
    o_cov[4 * k + 1] = m ? c01 : 0.0f;
    o_cov[4 * k + 2] = m ? c10 : 0.0f;
    o_cov[4 * k + 3] = m ? c11 : 0.0f;
  }

  // ---- store ----
  float4* op = reinterpret_cast<float4*>(out) + (size_t)3 * g;
  op[0] = make_float4(o_pos[0], o_pos[1], o_pos[2],  o_pos[3]);
  op[1] = make_float4(o_pos[4], o_pos[5], o_pos[6],  o_pos[7]);
  op[2] = make_float4(o_pos[8], o_pos[9], o_pos[10], o_pos[11]);

  float4* oc = reinterpret_cast<float4*>(out + (size_t)3 * n) + (size_t)4 * g;
#pragma unroll
  for (int k = 0; k < 4; ++k)
    oc[k] = make_float4(o_cov[4 * k + 0], o_cov[4 * k + 1],
                        o_cov[4 * k + 2], o_cov[4 * k + 3]);

  reinterpret_cast<float4*>(out + (size_t)7 * n)[g] =
      make_float4(o_msk[0], o_msk[1], o_msk[2], o_msk[3]);
}

extern "C" void kernel_launch(void* const* d_in, const int* in_sizes, int n_in,
                              void* d_out, int out_size, void* d_ws, size_t ws_size,
                              hipStream_t stream) {
  const float* pos3d = (const float*)d_in[0];
  const float* cov3d = (const float*)d_in[1];
  const float* view  = (const float*)d_in[2];
  const float* proj  = (const float*)d_in[3];

  const int n = in_sizes[0] / 3;            // 4,000,000

  const int ngroups = (n + 3) / 4;          // 1,000,000
  const int threads = 256;
  const int blocks  = (ngroups + threads - 1) / threads;

  cam_kernel<<<blocks, threads, 0, stream>>>(pos3d, cov3d, view, proj,
                                             (float*)d_out, n);
}